// Round 7
// baseline (682.347 us; speedup 1.0000x reference)
//
#include <hip/hip_runtime.h>
#include <math.h>

#define Bn 32
#define Fn 1024
#define Dn 256
#define Hn 4
#define En 64
#define FFn 4096
#define LN_EPS 1e-5f
#define NBLK 256
#define NTHR 512
#define GC8 8
#define GCH8 (Fn/GC8)    // 128
#define FC1 4
#define FCH1 (Fn/FC1)    // 256
#define JC2 16
#define JCH2 (FFn/JC2)   // 256

__device__ __forceinline__ float wsum(float v) {
#pragma unroll
    for (int off = 32; off; off >>= 1) v += __shfl_xor(v, off, 64);
    return v;
}

// grid barrier: all 256 blocks resident (1/CU) -> no deadlock. Sense-reversal.
__device__ __forceinline__ void gbar(unsigned* cnt, unsigned* sns, unsigned* bls) {
    __threadfence();          // release: all threads' writes flushed before arrive
    __syncthreads();
    if (threadIdx.x == 0) {
        unsigned my = *bls ^ 1u;
        unsigned v = __hip_atomic_fetch_add(cnt, 1u, __ATOMIC_ACQ_REL,
                                            __HIP_MEMORY_SCOPE_AGENT);
        if (v == NBLK - 1u) {
            __hip_atomic_store(cnt, 0u, __ATOMIC_RELAXED, __HIP_MEMORY_SCOPE_AGENT);
            __hip_atomic_store(sns, my, __ATOMIC_RELEASE, __HIP_MEMORY_SCOPE_AGENT);
        } else {
            while (__hip_atomic_load(sns, __ATOMIC_ACQUIRE,
                                     __HIP_MEMORY_SCOPE_AGENT) != my)
                __builtin_amdgcn_s_sleep(2);
        }
        *bls = my;
    }
    __syncthreads();
    __threadfence();          // acquire: invalidate stale cache lines
}

__global__ __launch_bounds__(NTHR) void fused(
    const float* __restrict__ x, const float* __restrict__ emb,
    const float* __restrict__ Wq, const float* __restrict__ Wk,
    const float* __restrict__ Wv, const float* __restrict__ Wo,
    const float* __restrict__ bo, const float* __restrict__ g1,
    const float* __restrict__ b1, const float* __restrict__ g2,
    const float* __restrict__ b2, const float* __restrict__ W1,
    const float* __restrict__ bf1, const float* __restrict__ W2,
    const float* __restrict__ bf2,
    float* __restrict__ EqT, float* __restrict__ Ekg, float* __restrict__ Evo,
    float* __restrict__ hbuf, float* __restrict__ TT8, float* __restrict__ xmid,
    float* __restrict__ h2b, float* __restrict__ C1p, float* __restrict__ U,
    float* __restrict__ C2p, unsigned* __restrict__ bar,
    float* __restrict__ out)
{
    __shared__ float sh[4096];     // 16 KB, reused per phase
    __shared__ unsigned bls;       // barrier local sense (tid0 only)
    const int bid = blockIdx.x, tid = threadIdx.x;
    const int wid = tid >> 6, lane = tid & 63;
    if (tid == 0) bls = 0;
    unsigned* cnt = bar;
    unsigned* sns = bar + 16;

    // ---------------- P1: LN1 (blocks 0..31) + tiled proj q,k,v (all 256) ----
    if (bid < Bn) {
        float2 v = ((const float2*)(x + bid * Fn))[tid];
        float s = wsum(v.x + v.y);
        if (lane == 0) sh[wid] = s;
        __syncthreads();
        float mu = 0.f;
#pragma unroll
        for (int w = 0; w < 8; w++) mu += sh[w];
        mu *= (1.f / Fn);
        float dx = v.x - mu, dy = v.y - mu;
        float vs = wsum(dx * dx + dy * dy);
        __syncthreads();
        if (lane == 0) sh[wid] = vs;
        __syncthreads();
        float var = 0.f;
#pragma unroll
        for (int w = 0; w < 8; w++) var += sh[w];
        var *= (1.f / Fn);
        float rs = rsqrtf(var + LN_EPS);
        float2 gv = ((const float2*)g1)[tid];
        float2 bv = ((const float2*)b1)[tid];
        float2 o;
        o.x = dx * rs * gv.x + bv.x;
        o.y = dy * rs * gv.y + bv.y;
        ((float2*)(hbuf + bid * Fn))[tid] = o;
        __syncthreads();
    }
    {
        const int h = bid >> 6, f0 = (bid & 63) * 16;
        const float4* e4 = (const float4*)(emb + (size_t)f0 * Dn);
        float4* s4 = (float4*)sh;
        s4[tid] = e4[tid];
        s4[tid + 512] = e4[tid + 512];
        float wol = Wo[h * En + lane];
        __syncthreads();
        const int fw = wid * 2;
        const float* wq = Wq + (size_t)h * Dn * En + lane;
        const float* wk = Wk + (size_t)h * Dn * En + lane;
        const float* wv = Wv + (size_t)h * Dn * En + lane;
        float aq0 = 0, aq1 = 0, ak0 = 0, ak1 = 0, av0 = 0, av1 = 0;
#pragma unroll 4
        for (int d = 0; d < Dn; d++) {
            float wqv = wq[(size_t)d * En];
            float wkv = wk[(size_t)d * En];
            float wvv = wv[(size_t)d * En];
            float e0 = sh[(fw + 0) * 256 + d];
            float e1 = sh[(fw + 1) * 256 + d];
            aq0 = fmaf(e0, wqv, aq0); aq1 = fmaf(e1, wqv, aq1);
            ak0 = fmaf(e0, wkv, ak0); ak1 = fmaf(e1, wkv, ak1);
            av0 = fmaf(e0, wvv, av0); av1 = fmaf(e1, wvv, av1);
        }
        int f = f0 + fw;
        EqT[((size_t)h * En + lane) * Fn + f]     = aq0 * 0.125f;
        EqT[((size_t)h * En + lane) * Fn + f + 1] = aq1 * 0.125f;
        Ekg[((size_t)h * Fn + f) * En + lane]     = ak0;
        Ekg[((size_t)h * Fn + f + 1) * En + lane] = ak1;
        float ev0 = wsum(av0 * wol);
        float ev1 = wsum(av1 * wol);
        if (lane == 0) { Evo[h * Fn + f] = ev0; Evo[h * Fn + f + 1] = ev1; }
    }
    gbar(cnt, sns, &bls);

    // ---------------- P2: TT8[gc][h][c][e], 2048 wave-units ----
    {
        int gw = bid * 8 + wid;
        int gc = gw >> 8;
        int hh = (gw >> 6) & 3;
        int c = gw & 63;
        const float* ek = Ekg + ((size_t)hh * Fn + gc * GCH8) * En + lane;
        float acc = 0.f;
        if (c < Bn) {
            const float* rp = hbuf + (size_t)c * Fn + gc * GCH8;
#pragma unroll 8
            for (int g = 0; g < GCH8; g++)
                acc = fmaf(rp[g], ek[(size_t)g * En], acc);
        } else {
            const float* hp = hbuf + (size_t)(c - Bn) * Fn + gc * GCH8;
            const float* ep = Evo + hh * Fn + gc * GCH8;
#pragma unroll 8
            for (int g = 0; g < GCH8; g++) {
                float hv = hp[g];
                acc = fmaf(hv * hv * ep[g], ek[(size_t)g * En], acc);
            }
        }
        TT8[(((size_t)gc * Hn + hh) * 64 + c) * 64 + lane] = acc;
    }
    gbar(cnt, sns, &bls);

    // ---------------- P3: attn combine + residual + LN2 (blocks 0..31) ----
    if (bid < Bn) {
        const int b = bid;
        {
            int cIsN = tid >> 8, hh = (tid >> 6) & 3, e = tid & 63;
            int c = cIsN ? (Bn + b) : b;
            float v = 0.f;
#pragma unroll
            for (int gc = 0; gc < GC8; gc++)
                v += TT8[(((size_t)gc * Hn + hh) * 64 + c) * 64 + e];
            sh[tid] = v;      // tt[cIsN][hh][e] at cIsN*256+hh*64+e == tid
        }
        float2 hv2 = *(const float2*)&hbuf[b * Fn + tid * 2];
        float pp[Hn];
#pragma unroll
        for (int hh = 0; hh < Hn; hh++) {
            float2 ev2 = *(const float2*)&Evo[hh * Fn + tid * 2];
            pp[hh] = hv2.x * ev2.x + hv2.y * ev2.y;
        }
#pragma unroll
        for (int hh = 0; hh < Hn; hh++) {
            pp[hh] = wsum(pp[hh]);
            if (lane == 0) sh[512 + hh * 8 + wid] = pp[hh];
        }
        __syncthreads();
        if (tid < Hn) {
            float s = 0.f;
#pragma unroll
            for (int w = 0; w < 8; w++) s += sh[512 + tid * 8 + w];
            sh[552 + tid] = s;
        }
        __syncthreads();
        float bov = bo[0];
        float2 xv = *(const float2*)&x[b * Fn + tid * 2];
        xv.x += bov; xv.y += bov;
#pragma unroll
        for (int hh = 0; hh < Hn; hh++) {
            float zdx = 0, zdy = 0, znx = 0, zny = 0;
            const float* eqb = EqT + (size_t)hh * En * Fn + tid * 2;
#pragma unroll 8
            for (int e = 0; e < En; e++) {
                float2 eq = *(const float2*)&eqb[(size_t)e * Fn];
                float td = sh[hh * 64 + e];
                float tn = sh[256 + hh * 64 + e];
                zdx = fmaf(eq.x, td, zdx); zdy = fmaf(eq.y, td, zdy);
                znx = fmaf(eq.x, tn, znx); zny = fmaf(eq.y, tn, zny);
            }
            float s0 = sh[552 + hh];
            xv.x += (s0 + hv2.x * znx) / (1024.0f + hv2.x * zdx);
            xv.y += (s0 + hv2.y * zny) / (1024.0f + hv2.y * zdy);
        }
        float s = wsum(xv.x + xv.y);
        if (lane == 0) sh[544 + wid] = s;
        __syncthreads();
        float mu = 0.f;
#pragma unroll
        for (int w = 0; w < 8; w++) mu += sh[544 + w];
        mu *= (1.f / Fn);
        float dx = xv.x - mu, dy = xv.y - mu;
        float vs = wsum(dx * dx + dy * dy);
        __syncthreads();
        if (lane == 0) sh[544 + wid] = vs;
        __syncthreads();
        float var = 0.f;
#pragma unroll
        for (int w = 0; w < 8; w++) var += sh[544 + w];
        var *= (1.f / Fn);
        float rs = rsqrtf(var + LN_EPS);
        *(float2*)&xmid[b * Fn + tid * 2] = xv;
        float2 g2v = ((const float2*)g2)[tid];
        float2 b2v = ((const float2*)b2)[tid];
        float2 hv;
        hv.x = dx * rs * g2v.x + b2v.x;
        hv.y = dy * rs * g2v.y + b2v.y;
        *(float2*)&h2b[b * Fn + tid * 2] = hv;
    }
    gbar(cnt, sns, &bls);

    // ---------------- P4: ffn1 split-K (64 jt x 4 fc = 256 blocks) ----
    {
        const int jt = bid & 63, fc = bid >> 6;
        const int j = jt * 64 + lane;
        const int bg = __builtin_amdgcn_readfirstlane(wid) * 4;
        const float* w = W1 + (size_t)(fc * FCH1) * FFn + j;
        const float* hb = h2b + fc * FCH1;
        float a0 = 0, a1 = 0, a2 = 0, a3 = 0;
#pragma unroll 4
        for (int f = 0; f < FCH1; f++) {
            float wv = w[(size_t)f * FFn];
            a0 = fmaf(hb[(size_t)(bg + 0) * Fn + f], wv, a0);
            a1 = fmaf(hb[(size_t)(bg + 1) * Fn + f], wv, a1);
            a2 = fmaf(hb[(size_t)(bg + 2) * Fn + f], wv, a2);
            a3 = fmaf(hb[(size_t)(bg + 3) * Fn + f], wv, a3);
        }
        C1p[((size_t)fc * Bn + bg + 0) * FFn + j] = a0;
        C1p[((size_t)fc * Bn + bg + 1) * FFn + j] = a1;
        C1p[((size_t)fc * Bn + bg + 2) * FFn + j] = a2;
        C1p[((size_t)fc * Bn + bg + 3) * FFn + j] = a3;
    }
    gbar(cnt, sns, &bls);

    // ---------------- P5: gelu (blocks 0..63 active) ----
    {
        int u = bid * NTHR + tid;
        if (u < Bn * FFn / 4) {
            int b = u >> 10, j4 = (u & 1023) * 4;
            float4 s5 = *(const float4*)&bf1[j4];
#pragma unroll
            for (int fc = 0; fc < FC1; fc++) {
                float4 c = *(const float4*)&C1p[((size_t)fc * Bn + b) * FFn + j4];
                s5.x += c.x; s5.y += c.y; s5.z += c.z; s5.w += c.w;
            }
            const float kk = 0.70710678118654752f;
            float4 uo;
            uo.x = 0.5f * s5.x * (1.f + erff(s5.x * kk));
            uo.y = 0.5f * s5.y * (1.f + erff(s5.y * kk));
            uo.z = 0.5f * s5.z * (1.f + erff(s5.z * kk));
            uo.w = 0.5f * s5.w * (1.f + erff(s5.w * kk));
            *(float4*)&U[(size_t)b * FFn + j4] = uo;
        }
    }
    gbar(cnt, sns, &bls);

    // ---------------- P6: ffn2 split-K (16 it x 16 jc = 256 blocks) ----
    {
        const int it = bid & 15, jc = bid >> 4;
        const int i = it * 64 + lane;
        const int bg = __builtin_amdgcn_readfirstlane(wid) * 4;
        const float* w = W2 + (size_t)(jc * JCH2) * Fn + i;
        const float* ub = U + jc * JCH2;
        float a0 = 0, a1 = 0, a2 = 0, a3 = 0;
#pragma unroll 4
        for (int jj = 0; jj < JCH2; jj++) {
            float wv = w[(size_t)jj * Fn];
            a0 = fmaf(ub[(size_t)(bg + 0) * FFn + jj], wv, a0);
            a1 = fmaf(ub[(size_t)(bg + 1) * FFn + jj], wv, a1);
            a2 = fmaf(ub[(size_t)(bg + 2) * FFn + jj], wv, a2);
            a3 = fmaf(ub[(size_t)(bg + 3) * FFn + jj], wv, a3);
        }
        C2p[((size_t)jc * Bn + bg + 0) * Fn + i] = a0;
        C2p[((size_t)jc * Bn + bg + 1) * Fn + i] = a1;
        C2p[((size_t)jc * Bn + bg + 2) * Fn + i] = a2;
        C2p[((size_t)jc * Bn + bg + 3) * Fn + i] = a3;
    }
    gbar(cnt, sns, &bls);

    // ---------------- P7: final add (blocks 0..15 active) ----
    {
        int u = bid * NTHR + tid;
        if (u < Bn * Fn / 4) {
            int b = u >> 8, f4 = (u & 255) * 4;
            float4 s7 = *(const float4*)&xmid[b * Fn + f4];
            float4 bv = *(const float4*)&bf2[f4];
            s7.x += bv.x; s7.y += bv.y; s7.z += bv.z; s7.w += bv.w;
#pragma unroll
            for (int jc = 0; jc < JC2; jc++) {
                float4 c = *(const float4*)&C2p[((size_t)jc * Bn + b) * Fn + f4];
                s7.x += c.x; s7.y += c.y; s7.z += c.z; s7.w += c.w;
            }
            *(float4*)&out[b * Fn + f4] = s7;
        }
    }
}

extern "C" void kernel_launch(void* const* d_in, const int* in_sizes, int n_in,
                              void* d_out, int out_size, void* d_ws, size_t ws_size,
                              hipStream_t stream) {
    (void)in_sizes; (void)n_in; (void)out_size; (void)ws_size;
    const float* x   = (const float*)d_in[0];
    const float* emb = (const float*)d_in[1];
    const float* Wq  = (const float*)d_in[2];
    const float* Wk  = (const float*)d_in[3];
    const float* Wv  = (const float*)d_in[4];
    const float* Wo  = (const float*)d_in[5];
    const float* bo  = (const float*)d_in[6];
    const float* g1  = (const float*)d_in[7];
    const float* b1  = (const float*)d_in[8];
    const float* g2  = (const float*)d_in[9];
    const float* b2  = (const float*)d_in[10];
    const float* W1  = (const float*)d_in[11];
    const float* bf1 = (const float*)d_in[12];
    const float* W2  = (const float*)d_in[13];
    const float* bf2 = (const float*)d_in[14];
    float* out = (float*)d_out;

    float* ws = (float*)d_ws;
    size_t o = 0;
    float* EqT  = ws + o; o += (size_t)Hn * En * Fn;       // 262144
    float* Ekg  = ws + o; o += (size_t)Hn * Fn * En;       // 262144
    float* Evo  = ws + o; o += (size_t)Hn * Fn;            // 4096
    float* hbuf = ws + o; o += (size_t)Bn * Fn;            // 32768
    float* TT8  = ws + o; o += (size_t)GC8 * Hn * 64 * 64; // 131072
    float* xmid = ws + o; o += (size_t)Bn * Fn;            // 32768
    float* h2b  = ws + o; o += (size_t)Bn * Fn;            // 32768
    float* C1p  = ws + o; o += (size_t)FC1 * Bn * FFn;     // 524288
    float* U    = ws + o; o += (size_t)Bn * FFn;           // 131072
    float* C2p  = ws + o; o += (size_t)JC2 * Bn * Fn;      // 524288

    unsigned* bar = (unsigned*)((char*)d_ws + (32u << 20));  // well past arrays
    hipMemsetAsync(bar, 0, 256, stream);

    fused<<<dim3(NBLK), NTHR, 0, stream>>>(
        x, emb, Wq, Wk, Wv, Wo, bo, g1, b1, g2, b2, W1, bf1, W2, bf2,
        EqT, Ekg, Evo, hbuf, TT8, xmid, h2b, C1p, U, C2p, bar, out);
}

// Round 8
// 134.242 us; speedup vs baseline: 5.0830x; 5.0830x over previous
//
#include <hip/hip_runtime.h>
#include <math.h>

#define Bn 32
#define Fn 1024
#define Dn 256
#define Hn 4
#define En 64
#define FFn 4096
#define LN_EPS 1e-5f

__device__ __forceinline__ float wsum(float v) {
#pragma unroll
    for (int off = 32; off; off >>= 1) v += __shfl_xor(v, off, 64);
    return v;
}
__device__ __forceinline__ float4 xr4(float4 v, int m) {
    v.x += __shfl_xor(v.x, m, 64);
    v.y += __shfl_xor(v.y, m, 64);
    v.z += __shfl_xor(v.z, m, 64);
    v.w += __shfl_xor(v.w, m, 64);
    return v;
}
#define FMA4(A, S, B) \
    A.x = fmaf(S, B.x, A.x); A.y = fmaf(S, B.y, A.y); \
    A.z = fmaf(S, B.z, A.z); A.w = fmaf(S, B.w, A.w);

// ---- k1: {LN1 (blocks 0..31)} | {proj f-tile16 (256 blocks): EqT, Ekg, Evo} @512thr
__global__ __launch_bounds__(512) void k1(
    const float* __restrict__ x, const float* __restrict__ g1,
    const float* __restrict__ b1, const float* __restrict__ emb,
    const float* __restrict__ Wq, const float* __restrict__ Wk,
    const float* __restrict__ Wv, const float* __restrict__ Wo,
    float* __restrict__ hbuf, float* __restrict__ EqT,
    float* __restrict__ Ekg, float* __restrict__ Evo)
{
    __shared__ float sh[4096];   // 16 KB
    const int bid = blockIdx.x, tid = threadIdx.x;
    const int wid = tid >> 6, lane = tid & 63;
    if (bid < Bn) {
        float2 v = ((const float2*)(x + bid * Fn))[tid];
        float s = wsum(v.x + v.y);
        if (lane == 0) sh[wid] = s;
        __syncthreads();
        float mu = 0.f;
#pragma unroll
        for (int w = 0; w < 8; w++) mu += sh[w];
        mu *= (1.f / Fn);
        float dx = v.x - mu, dy = v.y - mu;
        float vs = wsum(dx * dx + dy * dy);
        __syncthreads();
        if (lane == 0) sh[wid] = vs;
        __syncthreads();
        float var = 0.f;
#pragma unroll
        for (int w = 0; w < 8; w++) var += sh[w];
        var *= (1.f / Fn);
        float rs = rsqrtf(var + LN_EPS);
        float2 gv = ((const float2*)g1)[tid];
        float2 bv = ((const float2*)b1)[tid];
        float2 o;
        o.x = dx * rs * gv.x + bv.x;
        o.y = dy * rs * gv.y + bv.y;
        ((float2*)(hbuf + bid * Fn))[tid] = o;
    } else {
        const int idx = bid - Bn;        // 0..255
        const int h = idx >> 6, f0 = (idx & 63) * 16;
        const float4* e4 = (const float4*)(emb + (size_t)f0 * Dn);
        float4* s4 = (float4*)sh;
        s4[tid] = e4[tid];
        s4[tid + 512] = e4[tid + 512];
        const int es = lane & 15, gs = lane >> 4;
        float4 wo4 = *(const float4*)&Wo[h * En + es * 4];
        __syncthreads();
        const float* wqb = Wq + (size_t)h * Dn * En + es * 4;
        const float* wkb = Wk + (size_t)h * Dn * En + es * 4;
        const float* wvb = Wv + (size_t)h * Dn * En + es * 4;
        const int fl = wid * 2;
        float4 aq0 = {0,0,0,0}, aq1 = {0,0,0,0};
        float4 ak0 = {0,0,0,0}, ak1 = {0,0,0,0};
        float4 av0 = {0,0,0,0}, av1 = {0,0,0,0};
#pragma unroll 4
        for (int d0 = 0; d0 < Dn; d0 += 4) {
            int d = d0 + gs;
            float4 q4 = *(const float4*)&wqb[(size_t)d * En];
            float4 k4 = *(const float4*)&wkb[(size_t)d * En];
            float4 v4 = *(const float4*)&wvb[(size_t)d * En];
            float e0 = sh[fl * 256 + d];
            float e1 = sh[(fl + 1) * 256 + d];
            FMA4(aq0, e0, q4); FMA4(aq1, e1, q4);
            FMA4(ak0, e0, k4); FMA4(ak1, e1, k4);
            FMA4(av0, e0, v4); FMA4(av1, e1, v4);
        }
        aq0 = xr4(aq0, 16); aq0 = xr4(aq0, 32);
        aq1 = xr4(aq1, 16); aq1 = xr4(aq1, 32);
        ak0 = xr4(ak0, 16); ak0 = xr4(ak0, 32);
        ak1 = xr4(ak1, 16); ak1 = xr4(ak1, 32);
        av0 = xr4(av0, 16); av0 = xr4(av0, 32);
        av1 = xr4(av1, 16); av1 = xr4(av1, 32);
        // Evo: dot(av, wo) then reduce across 16 es lanes
        float p0 = av0.x * wo4.x + av0.y * wo4.y + av0.z * wo4.z + av0.w * wo4.w;
        float p1 = av1.x * wo4.x + av1.y * wo4.y + av1.z * wo4.z + av1.w * wo4.w;
#pragma unroll
        for (int m = 1; m < 16; m <<= 1) {
            p0 += __shfl_xor(p0, m, 64);
            p1 += __shfl_xor(p1, m, 64);
        }
        int f = f0 + fl;
        if (lane == 0) { Evo[h * Fn + f] = p0; Evo[h * Fn + f + 1] = p1; }
        if (gs == 0) {
            *(float4*)&Ekg[((size_t)h * Fn + f) * En + es * 4] = ak0;
            *(float4*)&Ekg[((size_t)h * Fn + f + 1) * En + es * 4] = ak1;
            const float sc = 0.125f;
            EqT[((size_t)h * En + es * 4 + 0) * Fn + f] = aq0.x * sc;
            EqT[((size_t)h * En + es * 4 + 1) * Fn + f] = aq0.y * sc;
            EqT[((size_t)h * En + es * 4 + 2) * Fn + f] = aq0.z * sc;
            EqT[((size_t)h * En + es * 4 + 3) * Fn + f] = aq0.w * sc;
            EqT[((size_t)h * En + es * 4 + 0) * Fn + f + 1] = aq1.x * sc;
            EqT[((size_t)h * En + es * 4 + 1) * Fn + f + 1] = aq1.y * sc;
            EqT[((size_t)h * En + es * 4 + 2) * Fn + f + 1] = aq1.z * sc;
            EqT[((size_t)h * En + es * 4 + 3) * Fn + f + 1] = aq1.w * sc;
        }
    }
}

// ---- k2: TT8[gc][h][c][e] (blocks 0..511) | U := bf1 rows (blocks 512..515)
__global__ __launch_bounds__(256) void k2(
    const float* __restrict__ hbuf, const float* __restrict__ Evo,
    const float* __restrict__ Ekg, const float* __restrict__ bf1,
    float* __restrict__ TT8, float* __restrict__ U)
{
    const int bid = blockIdx.x, tid = threadIdx.x;
    if (bid >= 512) {
        int t = (bid - 512) * 256 + tid;          // 0..1023
        const float4* b4 = (const float4*)bf1;
        float4* u4 = (float4*)U;
#pragma unroll
        for (int k = 0; k < 32; k++) {
            int idx = k * 1024 + t;               // 32768 float4
            u4[idx] = b4[idx & 1023];
        }
        return;
    }
    const int wid = tid >> 6, lane = tid & 63;
    const int u = bid * 4 + wid;                  // 0..2047
    const int gc = u >> 8, hh = (u >> 6) & 3, c = u & 63;
    const int es = lane & 15, gs = lane >> 4;
    const float* ekb = Ekg + ((size_t)hh * Fn + gc * 128) * En + es * 4;
    float4 acc = {0, 0, 0, 0};
    if (c < Bn) {
        const float* rp = hbuf + (size_t)c * Fn + gc * 128;
#pragma unroll 8
        for (int g0 = 0; g0 < 128; g0 += 4) {
            int g = g0 + gs;
            float r = rp[g];
            float4 ek = *(const float4*)&ekb[(size_t)g * En];
            FMA4(acc, r, ek);
        }
    } else {
        const float* hp = hbuf + (size_t)(c - Bn) * Fn + gc * 128;
        const float* ep = Evo + hh * Fn + gc * 128;
#pragma unroll 8
        for (int g0 = 0; g0 < 128; g0 += 4) {
            int g = g0 + gs;
            float hv = hp[g];
            float r = hv * hv * ep[g];
            float4 ek = *(const float4*)&ekb[(size_t)g * En];
            FMA4(acc, r, ek);
        }
    }
    acc = xr4(acc, 16); acc = xr4(acc, 32);
    if (gs == 0)
        *(float4*)&TT8[(((size_t)gc * Hn + hh) * 64 + c) * 64 + es * 4] = acc;
}

// ---- k3: attn combine + residual + LN2; writes out-base (=xmid+bf2) and h2T
__global__ __launch_bounds__(1024) void k3(
    const float* __restrict__ x, const float* __restrict__ hbuf,
    const float* __restrict__ TT8, const float* __restrict__ EqT,
    const float* __restrict__ Evo, const float* __restrict__ bo,
    const float* __restrict__ g2, const float* __restrict__ b2,
    const float* __restrict__ bf2,
    float* __restrict__ out, float* __restrict__ h2T)
{
    __shared__ float tt[512];      // [cIsN][h][e]
    __shared__ float sp[Hn][16];
    __shared__ float red[16];
    __shared__ float s0l[Hn];
    const int b = blockIdx.x, tid = threadIdx.x;
    const int wid = tid >> 6, lane = tid & 63;
    if (tid < 512) {
        int cIsN = tid >> 8, hh = (tid >> 6) & 3, e = tid & 63;
        int c = cIsN ? (Bn + b) : b;
        float v = 0.f;
#pragma unroll
        for (int gc = 0; gc < 8; gc++)
            v += TT8[(((size_t)gc * Hn + hh) * 64 + c) * 64 + e];
        tt[tid] = v;
    }
    const int f = tid;
    float hf = hbuf[b * Fn + f];
    float pp[Hn];
#pragma unroll
    for (int hh = 0; hh < Hn; hh++) pp[hh] = hf * Evo[hh * Fn + f];
#pragma unroll
    for (int hh = 0; hh < Hn; hh++) {
        float t = wsum(pp[hh]);
        if (lane == 0) sp[hh][wid] = t;
    }
    __syncthreads();
    if (tid < Hn) {
        float s = 0.f;
#pragma unroll
        for (int w = 0; w < 16; w++) s += sp[tid][w];
        s0l[tid] = s;
    }
    __syncthreads();
    float xv = x[b * Fn + f] + bo[0];
#pragma unroll
    for (int hh = 0; hh < Hn; hh++) {
        float zd = 0.f, zn = 0.f;
        const float* eqb = EqT + (size_t)hh * En * Fn + f;
#pragma unroll 8
        for (int e = 0; e < En; e++) {
            float eq = eqb[(size_t)e * Fn];
            zd = fmaf(eq, tt[hh * 64 + e], zd);
            zn = fmaf(eq, tt[256 + hh * 64 + e], zn);
        }
        xv += (s0l[hh] + hf * zn) / (1024.0f + hf * zd);
    }
    float s = wsum(xv);
    if (lane == 0) red[wid] = s;
    __syncthreads();
    float mu = 0.f;
#pragma unroll
    for (int w = 0; w < 16; w++) mu += red[w];
    mu *= (1.f / Fn);
    float dx = xv - mu;
    float vs = wsum(dx * dx);
    __syncthreads();
    if (lane == 0) red[wid] = vs;
    __syncthreads();
    float var = 0.f;
#pragma unroll
    for (int w = 0; w < 16; w++) var += red[w];
    var *= (1.f / Fn);
    float rs = rsqrtf(var + LN_EPS);
    out[b * Fn + f] = xv + bf2[f];
    h2T[f * Bn + b] = dx * rs * g2[f] + b2[f];
}

// ---- k4: ffn1 split-K-2, atomicAdd into U (pre-activation, bf1-initialized)
__global__ __launch_bounds__(256) void k4(
    const float* __restrict__ h2T, const float* __restrict__ W1,
    float* __restrict__ U)
{
    const int jt = blockIdx.x & 127, fc = blockIdx.x >> 7;
    const int tid = threadIdx.x;
    const int j = jt * 32 + (tid & 31);
    const int bg = (tid >> 5) * 4;
    const float* w = W1 + (size_t)(fc * 512) * FFn + j;
    const float* ht = h2T + (size_t)(fc * 512) * Bn + bg;
    float a0 = 0, a1 = 0, a2 = 0, a3 = 0;
#pragma unroll 8
    for (int f = 0; f < 512; f++) {
        float wv = w[(size_t)f * FFn];
        float4 h4 = *(const float4*)&ht[(size_t)f * Bn];
        a0 = fmaf(h4.x, wv, a0);
        a1 = fmaf(h4.y, wv, a1);
        a2 = fmaf(h4.z, wv, a2);
        a3 = fmaf(h4.w, wv, a3);
    }
    atomicAdd(&U[(size_t)(bg + 0) * FFn + j], a0);
    atomicAdd(&U[(size_t)(bg + 1) * FFn + j], a1);
    atomicAdd(&U[(size_t)(bg + 2) * FFn + j], a2);
    atomicAdd(&U[(size_t)(bg + 3) * FFn + j], a3);
}

// ---- k5: ffn2 split-K-16 with on-the-fly gelu; atomicAdd into out
__global__ __launch_bounds__(256) void k5(
    const float* __restrict__ U, const float* __restrict__ W2,
    float* __restrict__ out)
{
    __shared__ float sh[8192];     // [jj][b], linear LDS write
    const int it = blockIdx.x & 15, jc = blockIdx.x >> 4;
    const int tid = threadIdx.x;
    const float kk = 0.70710678118654752f;
#pragma unroll
    for (int k = 0; k < 32; k++) {
        int idx = k * 256 + tid;          // jj = idx>>5, b = idx&31
        int bb = idx & 31, jj = idx >> 5;
        float v = U[(size_t)bb * FFn + jc * 256 + jj];
        sh[idx] = 0.5f * v * (1.f + erff(v * kk));
    }
    __syncthreads();
    const int i = it * 64 + (tid & 63);
    const int bg = (tid >> 6) * 8;
    float acc[8] = {};
    const float* w = W2 + (size_t)(jc * 256) * Fn + i;
#pragma unroll 4
    for (int jj = 0; jj < 256; jj++) {
        float wv = w[(size_t)jj * Fn];
        float4 ua = *(const float4*)&sh[jj * 32 + bg];
        float4 ub = *(const float4*)&sh[jj * 32 + bg + 4];
        acc[0] = fmaf(ua.x, wv, acc[0]);
        acc[1] = fmaf(ua.y, wv, acc[1]);
        acc[2] = fmaf(ua.z, wv, acc[2]);
        acc[3] = fmaf(ua.w, wv, acc[3]);
        acc[4] = fmaf(ub.x, wv, acc[4]);
        acc[5] = fmaf(ub.y, wv, acc[5]);
        acc[6] = fmaf(ub.z, wv, acc[6]);
        acc[7] = fmaf(ub.w, wv, acc[7]);
    }
#pragma unroll
    for (int bb = 0; bb < 8; bb++)
        atomicAdd(&out[(size_t)(bg + bb) * Fn + i], acc[bb]);
}

extern "C" void kernel_launch(void* const* d_in, const int* in_sizes, int n_in,
                              void* d_out, int out_size, void* d_ws, size_t ws_size,
                              hipStream_t stream) {
    (void)in_sizes; (void)n_in; (void)out_size; (void)ws_size;
    const float* x   = (const float*)d_in[0];
    const float* emb = (const float*)d_in[1];
    const float* Wq  = (const float*)d_in[2];
    const float* Wk  = (const float*)d_in[3];
    const float* Wv  = (const float*)d_in[4];
    const float* Wo  = (const float*)d_in[5];
    const float* bo  = (const float*)d_in[6];
    const float* g1  = (const float*)d_in[7];
    const float* b1  = (const float*)d_in[8];
    const float* g2  = (const float*)d_in[9];
    const float* b2  = (const float*)d_in[10];
    const float* W1  = (const float*)d_in[11];
    const float* bf1 = (const float*)d_in[12];
    const float* W2  = (const float*)d_in[13];
    const float* bf2 = (const float*)d_in[14];
    float* out = (float*)d_out;

    float* ws = (float*)d_ws;
    size_t o = 0;
    float* EqT  = ws + o; o += (size_t)Hn * En * Fn;        // 262144
    float* Ekg  = ws + o; o += (size_t)Hn * Fn * En;        // 262144
    float* Evo  = ws + o; o += (size_t)Hn * Fn;             // 4096
    float* hbuf = ws + o; o += (size_t)Bn * Fn;             // 32768
    float* TT8  = ws + o; o += (size_t)8 * Hn * 64 * 64;    // 131072
    float* h2T  = ws + o; o += (size_t)Fn * Bn;             // 32768
    float* U    = ws + o; o += (size_t)Bn * FFn;            // 131072

    k1<<<dim3(Bn + 256), 512, 0, stream>>>(x, g1, b1, emb, Wq, Wk, Wv, Wo,
                                           hbuf, EqT, Ekg, Evo);
    k2<<<dim3(516), 256, 0, stream>>>(hbuf, Evo, Ekg, bf1, TT8, U);
    k3<<<dim3(Bn), 1024, 0, stream>>>(x, hbuf, TT8, EqT, Evo, bo, g2, b2, bf2,
                                      out, h2T);
    k4<<<dim3(256), 256, 0, stream>>>(h2T, W1, U);
    k5<<<dim3(256), 256, 0, stream>>>(U, W2, out);
}

// Round 9
// 118.705 us; speedup vs baseline: 5.7482x; 1.1309x over previous
//
#include <hip/hip_runtime.h>
#include <math.h>

#define Bn 32
#define Fn 1024
#define Dn 256
#define Hn 4
#define En 64
#define FFn 4096
#define LN_EPS 1e-5f

__device__ __forceinline__ float wsum(float v) {
#pragma unroll
    for (int off = 32; off; off >>= 1) v += __shfl_xor(v, off, 64);
    return v;
}
__device__ __forceinline__ float4 xr4(float4 v, int m) {
    v.x += __shfl_xor(v.x, m, 64);
    v.y += __shfl_xor(v.y, m, 64);
    v.z += __shfl_xor(v.z, m, 64);
    v.w += __shfl_xor(v.w, m, 64);
    return v;
}
#define FMA4(A, S, B) \
    A.x = fmaf(S, B.x, A.x); A.y = fmaf(S, B.y, A.y); \
    A.z = fmaf(S, B.z, A.z); A.w = fmaf(S, B.w, A.w);

// ---- k1: {LN1 (blocks 0..31)} | {proj f-tile16 (256 blocks): EqT, Ekg, Evo} @512thr
__global__ __launch_bounds__(512) void k1(
    const float* __restrict__ x, const float* __restrict__ g1,
    const float* __restrict__ b1, const float* __restrict__ emb,
    const float* __restrict__ Wq, const float* __restrict__ Wk,
    const float* __restrict__ Wv, const float* __restrict__ Wo,
    float* __restrict__ hbuf, float* __restrict__ EqT,
    float* __restrict__ Ekg, float* __restrict__ Evo)
{
    __shared__ float sh[4096];   // 16 KB
    const int bid = blockIdx.x, tid = threadIdx.x;
    const int wid = tid >> 6, lane = tid & 63;
    if (bid < Bn) {
        float2 v = ((const float2*)(x + bid * Fn))[tid];
        float s = wsum(v.x + v.y);
        if (lane == 0) sh[wid] = s;
        __syncthreads();
        float mu = 0.f;
#pragma unroll
        for (int w = 0; w < 8; w++) mu += sh[w];
        mu *= (1.f / Fn);
        float dx = v.x - mu, dy = v.y - mu;
        float vs = wsum(dx * dx + dy * dy);
        __syncthreads();
        if (lane == 0) sh[wid] = vs;
        __syncthreads();
        float var = 0.f;
#pragma unroll
        for (int w = 0; w < 8; w++) var += sh[w];
        var *= (1.f / Fn);
        float rs = rsqrtf(var + LN_EPS);
        float2 gv = ((const float2*)g1)[tid];
        float2 bv = ((const float2*)b1)[tid];
        float2 o;
        o.x = dx * rs * gv.x + bv.x;
        o.y = dy * rs * gv.y + bv.y;
        ((float2*)(hbuf + bid * Fn))[tid] = o;
    } else {
        const int idx = bid - Bn;        // 0..255
        const int h = idx >> 6, f0 = (idx & 63) * 16;
        const float4* e4 = (const float4*)(emb + (size_t)f0 * Dn);
        float4* s4 = (float4*)sh;
        s4[tid] = e4[tid];
        s4[tid + 512] = e4[tid + 512];
        const int es = lane & 15, gs = lane >> 4;
        float4 wo4 = *(const float4*)&Wo[h * En + es * 4];
        __syncthreads();
        const float* wqb = Wq + (size_t)h * Dn * En + es * 4;
        const float* wkb = Wk + (size_t)h * Dn * En + es * 4;
        const float* wvb = Wv + (size_t)h * Dn * En + es * 4;
        const int fl = wid * 2;
        float4 aq0 = {0,0,0,0}, aq1 = {0,0,0,0};
        float4 ak0 = {0,0,0,0}, ak1 = {0,0,0,0};
        float4 av0 = {0,0,0,0}, av1 = {0,0,0,0};
#pragma unroll 4
        for (int d0 = 0; d0 < Dn; d0 += 4) {
            int d = d0 + gs;
            float4 q4 = *(const float4*)&wqb[(size_t)d * En];
            float4 k4 = *(const float4*)&wkb[(size_t)d * En];
            float4 v4 = *(const float4*)&wvb[(size_t)d * En];
            float e0 = sh[fl * 256 + d];
            float e1 = sh[(fl + 1) * 256 + d];
            FMA4(aq0, e0, q4); FMA4(aq1, e1, q4);
            FMA4(ak0, e0, k4); FMA4(ak1, e1, k4);
            FMA4(av0, e0, v4); FMA4(av1, e1, v4);
        }
        aq0 = xr4(aq0, 16); aq0 = xr4(aq0, 32);
        aq1 = xr4(aq1, 16); aq1 = xr4(aq1, 32);
        ak0 = xr4(ak0, 16); ak0 = xr4(ak0, 32);
        ak1 = xr4(ak1, 16); ak1 = xr4(ak1, 32);
        av0 = xr4(av0, 16); av0 = xr4(av0, 32);
        av1 = xr4(av1, 16); av1 = xr4(av1, 32);
        float p0 = av0.x * wo4.x + av0.y * wo4.y + av0.z * wo4.z + av0.w * wo4.w;
        float p1 = av1.x * wo4.x + av1.y * wo4.y + av1.z * wo4.z + av1.w * wo4.w;
#pragma unroll
        for (int m = 1; m < 16; m <<= 1) {
            p0 += __shfl_xor(p0, m, 64);
            p1 += __shfl_xor(p1, m, 64);
        }
        int f = f0 + fl;
        if (lane == 0) { Evo[h * Fn + f] = p0; Evo[h * Fn + f + 1] = p1; }
        if (gs == 0) {
            *(float4*)&Ekg[((size_t)h * Fn + f) * En + es * 4] = ak0;
            *(float4*)&Ekg[((size_t)h * Fn + f + 1) * En + es * 4] = ak1;
            const float sc = 0.125f;
            EqT[((size_t)h * En + es * 4 + 0) * Fn + f] = aq0.x * sc;
            EqT[((size_t)h * En + es * 4 + 1) * Fn + f] = aq0.y * sc;
            EqT[((size_t)h * En + es * 4 + 2) * Fn + f] = aq0.z * sc;
            EqT[((size_t)h * En + es * 4 + 3) * Fn + f] = aq0.w * sc;
            EqT[((size_t)h * En + es * 4 + 0) * Fn + f + 1] = aq1.x * sc;
            EqT[((size_t)h * En + es * 4 + 1) * Fn + f + 1] = aq1.y * sc;
            EqT[((size_t)h * En + es * 4 + 2) * Fn + f + 1] = aq1.z * sc;
            EqT[((size_t)h * En + es * 4 + 3) * Fn + f + 1] = aq1.w * sc;
        }
    }
}

// ---- k2: TT8[gc][h][c][e] (512 blocks) ----
__global__ __launch_bounds__(256) void k2(
    const float* __restrict__ hbuf, const float* __restrict__ Evo,
    const float* __restrict__ Ekg, float* __restrict__ TT8)
{
    const int bid = blockIdx.x, tid = threadIdx.x;
    const int wid = tid >> 6, lane = tid & 63;
    const int u = bid * 4 + wid;                  // 0..2047
    const int gc = u >> 8, hh = (u >> 6) & 3, c = u & 63;
    const int es = lane & 15, gs = lane >> 4;
    const float* ekb = Ekg + ((size_t)hh * Fn + gc * 128) * En + es * 4;
    float4 acc = {0, 0, 0, 0};
    if (c < Bn) {
        const float* rp = hbuf + (size_t)c * Fn + gc * 128;
#pragma unroll 8
        for (int g0 = 0; g0 < 128; g0 += 4) {
            int g = g0 + gs;
            float r = rp[g];
            float4 ek = *(const float4*)&ekb[(size_t)g * En];
            FMA4(acc, r, ek);
        }
    } else {
        const float* hp = hbuf + (size_t)(c - Bn) * Fn + gc * 128;
        const float* ep = Evo + hh * Fn + gc * 128;
#pragma unroll 8
        for (int g0 = 0; g0 < 128; g0 += 4) {
            int g = g0 + gs;
            float hv = hp[g];
            float r = hv * hv * ep[g];
            float4 ek = *(const float4*)&ekb[(size_t)g * En];
            FMA4(acc, r, ek);
        }
    }
    acc = xr4(acc, 16); acc = xr4(acc, 32);
    if (gs == 0)
        *(float4*)&TT8[(((size_t)gc * Hn + hh) * 64 + c) * 64 + es * 4] = acc;
}

// ---- k3: attn combine + residual + LN2; writes out-base (=xmid+bf2) and h2T
__global__ __launch_bounds__(1024) void k3(
    const float* __restrict__ x, const float* __restrict__ hbuf,
    const float* __restrict__ TT8, const float* __restrict__ EqT,
    const float* __restrict__ Evo, const float* __restrict__ bo,
    const float* __restrict__ g2, const float* __restrict__ b2,
    const float* __restrict__ bf2,
    float* __restrict__ out, float* __restrict__ h2T)
{
    __shared__ float tt[512];      // [cIsN][h][e]
    __shared__ float sp[Hn][16];
    __shared__ float red[16];
    __shared__ float s0l[Hn];
    const int b = blockIdx.x, tid = threadIdx.x;
    const int wid = tid >> 6, lane = tid & 63;
    if (tid < 512) {
        int cIsN = tid >> 8, hh = (tid >> 6) & 3, e = tid & 63;
        int c = cIsN ? (Bn + b) : b;
        float v = 0.f;
#pragma unroll
        for (int gc = 0; gc < 8; gc++)
            v += TT8[(((size_t)gc * Hn + hh) * 64 + c) * 64 + e];
        tt[tid] = v;
    }
    const int f = tid;
    float hf = hbuf[b * Fn + f];
    float pp[Hn];
#pragma unroll
    for (int hh = 0; hh < Hn; hh++) pp[hh] = hf * Evo[hh * Fn + f];
#pragma unroll
    for (int hh = 0; hh < Hn; hh++) {
        float t = wsum(pp[hh]);
        if (lane == 0) sp[hh][wid] = t;
    }
    __syncthreads();
    if (tid < Hn) {
        float s = 0.f;
#pragma unroll
        for (int w = 0; w < 16; w++) s += sp[tid][w];
        s0l[tid] = s;
    }
    __syncthreads();
    float xv = x[b * Fn + f] + bo[0];
#pragma unroll
    for (int hh = 0; hh < Hn; hh++) {
        float zd = 0.f, zn = 0.f;
        const float* eqb = EqT + (size_t)hh * En * Fn + f;
#pragma unroll 8
        for (int e = 0; e < En; e++) {
            float eq = eqb[(size_t)e * Fn];
            zd = fmaf(eq, tt[hh * 64 + e], zd);
            zn = fmaf(eq, tt[256 + hh * 64 + e], zn);
        }
        xv += (s0l[hh] + hf * zn) / (1024.0f + hf * zd);
    }
    float s = wsum(xv);
    if (lane == 0) red[wid] = s;
    __syncthreads();
    float mu = 0.f;
#pragma unroll
    for (int w = 0; w < 16; w++) mu += red[w];
    mu *= (1.f / Fn);
    float dx = xv - mu;
    float vs = wsum(dx * dx);
    __syncthreads();
    if (lane == 0) red[wid] = vs;
    __syncthreads();
    float var = 0.f;
#pragma unroll
    for (int w = 0; w < 16; w++) var += red[w];
    var *= (1.f / Fn);
    float rs = rsqrtf(var + LN_EPS);
    out[b * Fn + f] = xv + bf2[f];
    h2T[f * Bn + b] = dx * rs * g2[f] + b2[f];
}

// ---- k4: ffn1 partials. grid (16 jt, 16 fc), 512 thr.
// C1p[fc][b][j] = sum_{f in chunk64} h2T[f][b] * W1[f][j]
__global__ __launch_bounds__(512) void k4(
    const float* __restrict__ h2T, const float* __restrict__ W1,
    float* __restrict__ C1p)
{
    __shared__ float h2s[64 * 32];   // 8 KB: [f][b]
    const int jt = blockIdx.x, fc = blockIdx.y;
    const int tid = threadIdx.x;
    const int wid = tid >> 6, lane = tid & 63;
    const int f0 = fc * 64;
    // stage h2T chunk: 2048 floats = 512 float4; [f][b] rows of 128 B
    {
        int fr = tid >> 3, b4 = (tid & 7) * 4;
        *(float4*)&h2s[fr * 32 + b4] = *(const float4*)&h2T[(size_t)(f0 + fr) * Bn + b4];
    }
    __syncthreads();
    const int j4 = jt * 256 + lane * 4;
    const int bg = wid * 4;
    const float* wb = W1 + (size_t)f0 * FFn + j4;
    float4 a0 = {0,0,0,0}, a1 = {0,0,0,0}, a2 = {0,0,0,0}, a3 = {0,0,0,0};
#pragma unroll 8
    for (int f = 0; f < 64; f++) {
        float4 w4 = *(const float4*)&wb[(size_t)f * FFn];
        float4 hb = *(const float4*)&h2s[f * 32 + bg];
        FMA4(a0, hb.x, w4);
        FMA4(a1, hb.y, w4);
        FMA4(a2, hb.z, w4);
        FMA4(a3, hb.w, w4);
    }
    float* cp = C1p + ((size_t)fc * Bn + bg) * FFn + j4;
    *(float4*)&cp[0 * FFn] = a0;
    *(float4*)&cp[1 * FFn] = a1;
    *(float4*)&cp[2 * FFn] = a2;
    *(float4*)&cp[3 * FFn] = a3;
}

// ---- k5: ffn2. grid (4 it, 16 jc), 512 thr.
// stage: ug[jj][b] = gelu(bf1 + sum_fc C1p[fc][b][jc*256+jj]) in LDS
// main:  acc[b] += ug[jj][b] * W2[jc*256+jj][i]; atomicAdd into out.
__global__ __launch_bounds__(512) void k5(
    const float* __restrict__ C1p, const float* __restrict__ bf1,
    const float* __restrict__ W2, float* __restrict__ out)
{
    __shared__ float ug[256 * 32];   // 32 KB: [jj][b]
    const int it = blockIdx.x, jc = blockIdx.y;
    const int tid = threadIdx.x;
    const int wid = tid >> 6, lane = tid & 63;
    const float kk = 0.70710678118654752f;
#pragma unroll
    for (int k = 0; k < 4; k++) {
        int idx = k * 512 + tid;           // 2048 float4 units
        int b = idx & 31, jq = idx >> 5;   // jq 0..63
        const float* cb = C1p + (size_t)b * FFn + jc * 256 + jq * 4;
        float4 s = *(const float4*)&bf1[jc * 256 + jq * 4];
#pragma unroll
        for (int fc = 0; fc < 16; fc++) {
            float4 c = *(const float4*)&cb[(size_t)fc * Bn * FFn];
            s.x += c.x; s.y += c.y; s.z += c.z; s.w += c.w;
        }
        ug[(jq * 4 + 0) * 32 + b] = 0.5f * s.x * (1.f + erff(s.x * kk));
        ug[(jq * 4 + 1) * 32 + b] = 0.5f * s.y * (1.f + erff(s.y * kk));
        ug[(jq * 4 + 2) * 32 + b] = 0.5f * s.z * (1.f + erff(s.z * kk));
        ug[(jq * 4 + 3) * 32 + b] = 0.5f * s.w * (1.f + erff(s.w * kk));
    }
    __syncthreads();
    const int i4 = it * 256 + lane * 4;
    const int bg = wid * 4;
    const float* wb = W2 + (size_t)(jc * 256) * Fn + i4;
    float4 a0 = {0,0,0,0}, a1 = {0,0,0,0}, a2 = {0,0,0,0}, a3 = {0,0,0,0};
#pragma unroll 8
    for (int jj = 0; jj < 256; jj++) {
        float4 w4 = *(const float4*)&wb[(size_t)jj * Fn];
        float4 hb = *(const float4*)&ug[jj * 32 + bg];
        FMA4(a0, hb.x, w4);
        FMA4(a1, hb.y, w4);
        FMA4(a2, hb.z, w4);
        FMA4(a3, hb.w, w4);
    }
    float* ob = out + (size_t)bg * Fn + i4;
    atomicAdd(&ob[0 * Fn + 0], a0.x); atomicAdd(&ob[0 * Fn + 1], a0.y);
    atomicAdd(&ob[0 * Fn + 2], a0.z); atomicAdd(&ob[0 * Fn + 3], a0.w);
    atomicAdd(&ob[1 * Fn + 0], a1.x); atomicAdd(&ob[1 * Fn + 1], a1.y);
    atomicAdd(&ob[1 * Fn + 2], a1.z); atomicAdd(&ob[1 * Fn + 3], a1.w);
    atomicAdd(&ob[2 * Fn + 0], a2.x); atomicAdd(&ob[2 * Fn + 1], a2.y);
    atomicAdd(&ob[2 * Fn + 2], a2.z); atomicAdd(&ob[2 * Fn + 3], a2.w);
    atomicAdd(&ob[3 * Fn + 0], a3.x); atomicAdd(&ob[3 * Fn + 1], a3.y);
    atomicAdd(&ob[3 * Fn + 2], a3.z); atomicAdd(&ob[3 * Fn + 3], a3.w);
}

extern "C" void kernel_launch(void* const* d_in, const int* in_sizes, int n_in,
                              void* d_out, int out_size, void* d_ws, size_t ws_size,
                              hipStream_t stream) {
    (void)in_sizes; (void)n_in; (void)out_size; (void)ws_size;
    const float* x   = (const float*)d_in[0];
    const float* emb = (const float*)d_in[1];
    const float* Wq  = (const float*)d_in[2];
    const float* Wk  = (const float*)d_in[3];
    const float* Wv  = (const float*)d_in[4];
    const float* Wo  = (const float*)d_in[5];
    const float* bo  = (const float*)d_in[6];
    const float* g1  = (const float*)d_in[7];
    const float* b1  = (const float*)d_in[8];
    const float* g2  = (const float*)d_in[9];
    const float* b2  = (const float*)d_in[10];
    const float* W1  = (const float*)d_in[11];
    const float* bf1 = (const float*)d_in[12];
    const float* W2  = (const float*)d_in[13];
    const float* bf2 = (const float*)d_in[14];
    float* out = (float*)d_out;

    float* ws = (float*)d_ws;
    size_t o = 0;
    float* EqT  = ws + o; o += (size_t)Hn * En * Fn;        // 262144
    float* Ekg  = ws + o; o += (size_t)Hn * Fn * En;        // 262144
    float* Evo  = ws + o; o += (size_t)Hn * Fn;             // 4096
    float* hbuf = ws + o; o += (size_t)Bn * Fn;             // 32768
    float* TT8  = ws + o; o += (size_t)8 * Hn * 64 * 64;    // 131072
    float* h2T  = ws + o; o += (size_t)Fn * Bn;             // 32768
    float* C1p  = ws + o; o += (size_t)16 * Bn * FFn;       // 2097152

    k1<<<dim3(Bn + 256), 512, 0, stream>>>(x, g1, b1, emb, Wq, Wk, Wv, Wo,
                                           hbuf, EqT, Ekg, Evo);
    k2<<<dim3(512), 256, 0, stream>>>(hbuf, Evo, Ekg, TT8);
    k3<<<dim3(Bn), 1024, 0, stream>>>(x, hbuf, TT8, EqT, Evo, bo, g2, b2, bf2,
                                      out, h2T);
    k4<<<dim3(16, 16), 512, 0, stream>>>(h2T, W1, C1p);
    k5<<<dim3(4, 16), 512, 0, stream>>>(C1p, bf1, W2, out);
}

// Round 10
// 91.304 us; speedup vs baseline: 7.4733x; 1.3001x over previous
//
#include <hip/hip_runtime.h>
#include <math.h>

#define Bn 32
#define Fn 1024
#define Dn 256
#define Hn 4
#define En 64
#define FFn 4096
#define LN_EPS 1e-5f

__device__ __forceinline__ float wsum(float v) {
#pragma unroll
    for (int off = 32; off; off >>= 1) v += __shfl_xor(v, off, 64);
    return v;
}
__device__ __forceinline__ float4 xr4(float4 v, int m) {
    v.x += __shfl_xor(v.x, m, 64);
    v.y += __shfl_xor(v.y, m, 64);
    v.z += __shfl_xor(v.z, m, 64);
    v.w += __shfl_xor(v.w, m, 64);
    return v;
}
#define FMA4(A, S, B) \
    A.x = fmaf(S, B.x, A.x); A.y = fmaf(S, B.y, A.y); \
    A.z = fmaf(S, B.z, A.z); A.w = fmaf(S, B.w, A.w);

// ---- k1: {LN1 (blocks 0..31)} | {proj f-tile16 (256 blocks): EqT, Ekg, Evo} @512thr
__global__ __launch_bounds__(512) void k1(
    const float* __restrict__ x, const float* __restrict__ g1,
    const float* __restrict__ b1, const float* __restrict__ emb,
    const float* __restrict__ Wq, const float* __restrict__ Wk,
    const float* __restrict__ Wv, const float* __restrict__ Wo,
    float* __restrict__ hbuf, float* __restrict__ EqT,
    float* __restrict__ Ekg, float* __restrict__ Evo)
{
    __shared__ float sh[4096];   // 16 KB
    const int bid = blockIdx.x, tid = threadIdx.x;
    const int wid = tid >> 6, lane = tid & 63;
    if (bid < Bn) {
        float2 v = ((const float2*)(x + bid * Fn))[tid];
        float s = wsum(v.x + v.y);
        if (lane == 0) sh[wid] = s;
        __syncthreads();
        float mu = 0.f;
#pragma unroll
        for (int w = 0; w < 8; w++) mu += sh[w];
        mu *= (1.f / Fn);
        float dx = v.x - mu, dy = v.y - mu;
        float vs = wsum(dx * dx + dy * dy);
        __syncthreads();
        if (lane == 0) sh[wid] = vs;
        __syncthreads();
        float var = 0.f;
#pragma unroll
        for (int w = 0; w < 8; w++) var += sh[w];
        var *= (1.f / Fn);
        float rs = rsqrtf(var + LN_EPS);
        float2 gv = ((const float2*)g1)[tid];
        float2 bv = ((const float2*)b1)[tid];
        float2 o;
        o.x = dx * rs * gv.x + bv.x;
        o.y = dy * rs * gv.y + bv.y;
        ((float2*)(hbuf + bid * Fn))[tid] = o;
    } else {
        const int idx = bid - Bn;        // 0..255
        const int h = idx >> 6, f0 = (idx & 63) * 16;
        const float4* e4 = (const float4*)(emb + (size_t)f0 * Dn);
        float4* s4 = (float4*)sh;
        s4[tid] = e4[tid];
        s4[tid + 512] = e4[tid + 512];
        const int es = lane & 15, gs = lane >> 4;
        float4 wo4 = *(const float4*)&Wo[h * En + es * 4];
        __syncthreads();
        const float* wqb = Wq + (size_t)h * Dn * En + es * 4;
        const float* wkb = Wk + (size_t)h * Dn * En + es * 4;
        const float* wvb = Wv + (size_t)h * Dn * En + es * 4;
        const int fl = wid * 2;
        float4 aq0 = {0,0,0,0}, aq1 = {0,0,0,0};
        float4 ak0 = {0,0,0,0}, ak1 = {0,0,0,0};
        float4 av0 = {0,0,0,0}, av1 = {0,0,0,0};
#pragma unroll 4
        for (int d0 = 0; d0 < Dn; d0 += 4) {
            int d = d0 + gs;
            float4 q4 = *(const float4*)&wqb[(size_t)d * En];
            float4 k4 = *(const float4*)&wkb[(size_t)d * En];
            float4 v4 = *(const float4*)&wvb[(size_t)d * En];
            float e0 = sh[fl * 256 + d];
            float e1 = sh[(fl + 1) * 256 + d];
            FMA4(aq0, e0, q4); FMA4(aq1, e1, q4);
            FMA4(ak0, e0, k4); FMA4(ak1, e1, k4);
            FMA4(av0, e0, v4); FMA4(av1, e1, v4);
        }
        aq0 = xr4(aq0, 16); aq0 = xr4(aq0, 32);
        aq1 = xr4(aq1, 16); aq1 = xr4(aq1, 32);
        ak0 = xr4(ak0, 16); ak0 = xr4(ak0, 32);
        ak1 = xr4(ak1, 16); ak1 = xr4(ak1, 32);
        av0 = xr4(av0, 16); av0 = xr4(av0, 32);
        av1 = xr4(av1, 16); av1 = xr4(av1, 32);
        float p0 = av0.x * wo4.x + av0.y * wo4.y + av0.z * wo4.z + av0.w * wo4.w;
        float p1 = av1.x * wo4.x + av1.y * wo4.y + av1.z * wo4.z + av1.w * wo4.w;
#pragma unroll
        for (int m = 1; m < 16; m <<= 1) {
            p0 += __shfl_xor(p0, m, 64);
            p1 += __shfl_xor(p1, m, 64);
        }
        int f = f0 + fl;
        if (lane == 0) { Evo[h * Fn + f] = p0; Evo[h * Fn + f + 1] = p1; }
        if (gs == 0) {
            *(float4*)&Ekg[((size_t)h * Fn + f) * En + es * 4] = ak0;
            *(float4*)&Ekg[((size_t)h * Fn + f + 1) * En + es * 4] = ak1;
            const float sc = 0.125f;
            EqT[((size_t)h * En + es * 4 + 0) * Fn + f] = aq0.x * sc;
            EqT[((size_t)h * En + es * 4 + 1) * Fn + f] = aq0.y * sc;
            EqT[((size_t)h * En + es * 4 + 2) * Fn + f] = aq0.z * sc;
            EqT[((size_t)h * En + es * 4 + 3) * Fn + f] = aq0.w * sc;
            EqT[((size_t)h * En + es * 4 + 0) * Fn + f + 1] = aq1.x * sc;
            EqT[((size_t)h * En + es * 4 + 1) * Fn + f + 1] = aq1.y * sc;
            EqT[((size_t)h * En + es * 4 + 2) * Fn + f + 1] = aq1.z * sc;
            EqT[((size_t)h * En + es * 4 + 3) * Fn + f + 1] = aq1.w * sc;
        }
    }
}

// ---- k2: TT8[gc][h][c][e] (512 blocks) ----
__global__ __launch_bounds__(256) void k2(
    const float* __restrict__ hbuf, const float* __restrict__ Evo,
    const float* __restrict__ Ekg, float* __restrict__ TT8)
{
    const int bid = blockIdx.x, tid = threadIdx.x;
    const int wid = tid >> 6, lane = tid & 63;
    const int u = bid * 4 + wid;                  // 0..2047
    const int gc = u >> 8, hh = (u >> 6) & 3, c = u & 63;
    const int es = lane & 15, gs = lane >> 4;
    const float* ekb = Ekg + ((size_t)hh * Fn + gc * 128) * En + es * 4;
    float4 acc = {0, 0, 0, 0};
    if (c < Bn) {
        const float* rp = hbuf + (size_t)c * Fn + gc * 128;
#pragma unroll 8
        for (int g0 = 0; g0 < 128; g0 += 4) {
            int g = g0 + gs;
            float r = rp[g];
            float4 ek = *(const float4*)&ekb[(size_t)g * En];
            FMA4(acc, r, ek);
        }
    } else {
        const float* hp = hbuf + (size_t)(c - Bn) * Fn + gc * 128;
        const float* ep = Evo + hh * Fn + gc * 128;
#pragma unroll 8
        for (int g0 = 0; g0 < 128; g0 += 4) {
            int g = g0 + gs;
            float hv = hp[g];
            float r = hv * hv * ep[g];
            float4 ek = *(const float4*)&ekb[(size_t)g * En];
            FMA4(acc, r, ek);
        }
    }
    acc = xr4(acc, 16); acc = xr4(acc, 32);
    if (gs == 0)
        *(float4*)&TT8[(((size_t)gc * Hn + hh) * 64 + c) * 64 + es * 4] = acc;
}

// ---- k3: attn combine + residual + LN2; writes out-base (=xmid+bf2) and h2T
__global__ __launch_bounds__(1024) void k3(
    const float* __restrict__ x, const float* __restrict__ hbuf,
    const float* __restrict__ TT8, const float* __restrict__ EqT,
    const float* __restrict__ Evo, const float* __restrict__ bo,
    const float* __restrict__ g2, const float* __restrict__ b2,
    const float* __restrict__ bf2,
    float* __restrict__ out, float* __restrict__ h2T)
{
    __shared__ float tt[512];      // [cIsN][h][e]
    __shared__ float sp[Hn][16];
    __shared__ float red[16];
    __shared__ float s0l[Hn];
    const int b = blockIdx.x, tid = threadIdx.x;
    const int wid = tid >> 6, lane = tid & 63;
    if (tid < 512) {
        int cIsN = tid >> 8, hh = (tid >> 6) & 3, e = tid & 63;
        int c = cIsN ? (Bn + b) : b;
        float v = 0.f;
#pragma unroll
        for (int gc = 0; gc < 8; gc++)
            v += TT8[(((size_t)gc * Hn + hh) * 64 + c) * 64 + e];
        tt[tid] = v;
    }
    const int f = tid;
    float hf = hbuf[b * Fn + f];
    float pp[Hn];
#pragma unroll
    for (int hh = 0; hh < Hn; hh++) pp[hh] = hf * Evo[hh * Fn + f];
#pragma unroll
    for (int hh = 0; hh < Hn; hh++) {
        float t = wsum(pp[hh]);
        if (lane == 0) sp[hh][wid] = t;
    }
    __syncthreads();
    if (tid < Hn) {
        float s = 0.f;
#pragma unroll
        for (int w = 0; w < 16; w++) s += sp[tid][w];
        s0l[tid] = s;
    }
    __syncthreads();
    float xv = x[b * Fn + f] + bo[0];
#pragma unroll
    for (int hh = 0; hh < Hn; hh++) {
        float zd = 0.f, zn = 0.f;
        const float* eqb = EqT + (size_t)hh * En * Fn + f;
#pragma unroll 8
        for (int e = 0; e < En; e++) {
            float eq = eqb[(size_t)e * Fn];
            zd = fmaf(eq, tt[hh * 64 + e], zd);
            zn = fmaf(eq, tt[256 + hh * 64 + e], zn);
        }
        xv += (s0l[hh] + hf * zn) / (1024.0f + hf * zd);
    }
    float s = wsum(xv);
    if (lane == 0) red[wid] = s;
    __syncthreads();
    float mu = 0.f;
#pragma unroll
    for (int w = 0; w < 16; w++) mu += red[w];
    mu *= (1.f / Fn);
    float dx = xv - mu;
    float vs = wsum(dx * dx);
    __syncthreads();
    if (lane == 0) red[wid] = vs;
    __syncthreads();
    float var = 0.f;
#pragma unroll
    for (int w = 0; w < 16; w++) var += red[w];
    var *= (1.f / Fn);
    float rs = rsqrtf(var + LN_EPS);
    out[b * Fn + f] = xv + bf2[f];
    h2T[f * Bn + b] = dx * rs * g2[f] + b2[f];
}

// ---- k4: ffn1 partials. grid (16 jt, 16 fc), 512 thr.
// C1p[fc][b][j] = sum_{f in chunk64} h2T[f][b] * W1[f][j]
__global__ __launch_bounds__(512) void k4(
    const float* __restrict__ h2T, const float* __restrict__ W1,
    float* __restrict__ C1p)
{
    __shared__ float h2s[64 * 32];   // 8 KB: [f][b]
    const int jt = blockIdx.x, fc = blockIdx.y;
    const int tid = threadIdx.x;
    const int wid = tid >> 6, lane = tid & 63;
    const int f0 = fc * 64;
    {
        int fr = tid >> 3, b4 = (tid & 7) * 4;
        *(float4*)&h2s[fr * 32 + b4] = *(const float4*)&h2T[(size_t)(f0 + fr) * Bn + b4];
    }
    __syncthreads();
    const int j4 = jt * 256 + lane * 4;
    const int bg = wid * 4;
    const float* wb = W1 + (size_t)f0 * FFn + j4;
    float4 a0 = {0,0,0,0}, a1 = {0,0,0,0}, a2 = {0,0,0,0}, a3 = {0,0,0,0};
#pragma unroll 8
    for (int f = 0; f < 64; f++) {
        float4 w4 = *(const float4*)&wb[(size_t)f * FFn];
        float4 hb = *(const float4*)&h2s[f * 32 + bg];
        FMA4(a0, hb.x, w4);
        FMA4(a1, hb.y, w4);
        FMA4(a2, hb.z, w4);
        FMA4(a3, hb.w, w4);
    }
    float* cp = C1p + ((size_t)fc * Bn + bg) * FFn + j4;
    *(float4*)&cp[0 * FFn] = a0;
    *(float4*)&cp[1 * FFn] = a1;
    *(float4*)&cp[2 * FFn] = a2;
    *(float4*)&cp[3 * FFn] = a3;
}

// ---- k4b: UT[j][b] = gelu(bf1[j] + sum_fc C1p[fc][b][j]).
// grid 64 blocks (b 32 x jh 2) x 256 thr; j-contiguous reads, scattered stores.
__global__ __launch_bounds__(256) void k4b(
    const float* __restrict__ C1p, const float* __restrict__ bf1,
    float* __restrict__ UT)
{
    const int b = blockIdx.x >> 1, jh = blockIdx.x & 1;
    const int j8 = jh * 2048 + threadIdx.x * 8;
    float4 s0 = *(const float4*)&bf1[j8];
    float4 s1 = *(const float4*)&bf1[j8 + 4];
    const float* cb = C1p + (size_t)b * FFn + j8;
#pragma unroll
    for (int fc = 0; fc < 16; fc++) {
        float4 c0 = *(const float4*)&cb[(size_t)fc * Bn * FFn];
        float4 c1 = *(const float4*)&cb[(size_t)fc * Bn * FFn + 4];
        s0.x += c0.x; s0.y += c0.y; s0.z += c0.z; s0.w += c0.w;
        s1.x += c1.x; s1.y += c1.y; s1.z += c1.z; s1.w += c1.w;
    }
    const float kk = 0.70710678118654752f;
    float u[8] = {s0.x, s0.y, s0.z, s0.w, s1.x, s1.y, s1.z, s1.w};
#pragma unroll
    for (int r = 0; r < 8; r++)
        UT[(size_t)(j8 + r) * Bn + b] = 0.5f * u[r] * (1.f + erff(u[r] * kk));
}

// ---- k5: ffn2. grid 256 blocks (it 16 x jc 16), 512 thr.
// stage: linear copy UT slice [256 jj][32 b] -> LDS.  main: per wave 4jj x 64i
// float4 W2 loads; acc[4b][4i]; jg-shfl reduce; fan-in-16 atomicAdd into out.
__global__ __launch_bounds__(512) void k5(
    const float* __restrict__ UT, const float* __restrict__ W2,
    float* __restrict__ out)
{
    __shared__ float ug[256 * 32];   // 32 KB: [jj][b]
    const int it = blockIdx.x & 15, jc = blockIdx.x >> 4;
    const int tid = threadIdx.x;
    const int wid = tid >> 6, lane = tid & 63;
    {
        const float4* src = (const float4*)(UT + (size_t)jc * 256 * Bn);
        float4* dst = (float4*)ug;
#pragma unroll
        for (int k = 0; k < 4; k++)
            dst[k * 512 + tid] = src[k * 512 + tid];
    }
    __syncthreads();
    const int jg = lane >> 4, il = lane & 15;
    const int i0 = it * 64 + il * 4;
    const int bg = wid * 4;
    const float* wb = W2 + (size_t)(jc * 256 + jg) * Fn + i0;
    float4 a0 = {0,0,0,0}, a1 = {0,0,0,0}, a2 = {0,0,0,0}, a3 = {0,0,0,0};
#pragma unroll 8
    for (int jj0 = 0; jj0 < 256; jj0 += 4) {
        float4 w4 = *(const float4*)&wb[(size_t)jj0 * Fn];
        float4 u4 = *(const float4*)&ug[(jj0 + jg) * 32 + bg];
        FMA4(a0, u4.x, w4);
        FMA4(a1, u4.y, w4);
        FMA4(a2, u4.z, w4);
        FMA4(a3, u4.w, w4);
    }
    a0 = xr4(a0, 16); a0 = xr4(a0, 32);
    a1 = xr4(a1, 16); a1 = xr4(a1, 32);
    a2 = xr4(a2, 16); a2 = xr4(a2, 32);
    a3 = xr4(a3, 16); a3 = xr4(a3, 32);
    if (jg == 0) {
        float* ob = out + (size_t)bg * Fn + i0;
        atomicAdd(&ob[0 * Fn + 0], a0.x); atomicAdd(&ob[0 * Fn + 1], a0.y);
        atomicAdd(&ob[0 * Fn + 2], a0.z); atomicAdd(&ob[0 * Fn + 3], a0.w);
        atomicAdd(&ob[1 * Fn + 0], a1.x); atomicAdd(&ob[1 * Fn + 1], a1.y);
        atomicAdd(&ob[1 * Fn + 2], a1.z); atomicAdd(&ob[1 * Fn + 3], a1.w);
        atomicAdd(&ob[2 * Fn + 0], a2.x); atomicAdd(&ob[2 * Fn + 1], a2.y);
        atomicAdd(&ob[2 * Fn + 2], a2.z); atomicAdd(&ob[2 * Fn + 3], a2.w);
        atomicAdd(&ob[3 * Fn + 0], a3.x); atomicAdd(&ob[3 * Fn + 1], a3.y);
        atomicAdd(&ob[3 * Fn + 2], a3.z); atomicAdd(&ob[3 * Fn + 3], a3.w);
    }
}

extern "C" void kernel_launch(void* const* d_in, const int* in_sizes, int n_in,
                              void* d_out, int out_size, void* d_ws, size_t ws_size,
                              hipStream_t stream) {
    (void)in_sizes; (void)n_in; (void)out_size; (void)ws_size;
    const float* x   = (const float*)d_in[0];
    const float* emb = (const float*)d_in[1];
    const float* Wq  = (const float*)d_in[2];
    const float* Wk  = (const float*)d_in[3];
    const float* Wv  = (const float*)d_in[4];
    const float* Wo  = (const float*)d_in[5];
    const float* bo  = (const float*)d_in[6];
    const float* g1  = (const float*)d_in[7];
    const float* b1  = (const float*)d_in[8];
    const float* g2  = (const float*)d_in[9];
    const float* b2  = (const float*)d_in[10];
    const float* W1  = (const float*)d_in[11];
    const float* bf1 = (const float*)d_in[12];
    const float* W2  = (const float*)d_in[13];
    const float* bf2 = (const float*)d_in[14];
    float* out = (float*)d_out;

    float* ws = (float*)d_ws;
    size_t o = 0;
    float* EqT  = ws + o; o += (size_t)Hn * En * Fn;        // 262144
    float* Ekg  = ws + o; o += (size_t)Hn * Fn * En;        // 262144
    float* Evo  = ws + o; o += (size_t)Hn * Fn;             // 4096
    float* hbuf = ws + o; o += (size_t)Bn * Fn;             // 32768
    float* TT8  = ws + o; o += (size_t)8 * Hn * 64 * 64;    // 131072
    float* h2T  = ws + o; o += (size_t)Fn * Bn;             // 32768
    float* C1p  = ws + o; o += (size_t)16 * Bn * FFn;       // 2097152
    float* UT   = ws + o; o += (size_t)FFn * Bn;            // 131072

    k1<<<dim3(Bn + 256), 512, 0, stream>>>(x, g1, b1, emb, Wq, Wk, Wv, Wo,
                                           hbuf, EqT, Ekg, Evo);
    k2<<<dim3(512), 256, 0, stream>>>(hbuf, Evo, Ekg, TT8);
    k3<<<dim3(Bn), 1024, 0, stream>>>(x, hbuf, TT8, EqT, Evo, bo, g2, b2, bf2,
                                      out, h2T);
    k4<<<dim3(16, 16), 512, 0, stream>>>(h2T, W1, C1p);
    k4b<<<dim3(64), 256, 0, stream>>>(C1p, bf1, UT);
    k5<<<dim3(256), 512, 0, stream>>>(UT, W2, out);
}

// Round 11
// 71.847 us; speedup vs baseline: 9.4972x; 1.2708x over previous
//
#include <hip/hip_runtime.h>
#include <math.h>

#define Bn 32
#define Fn 1024
#define Dn 256
#define Hn 4
#define En 64
#define FFn 4096
#define LN_EPS 1e-5f

__device__ __forceinline__ float wsum(float v) {
#pragma unroll
    for (int off = 32; off; off >>= 1) v += __shfl_xor(v, off, 64);
    return v;
}
__device__ __forceinline__ float4 xr4(float4 v, int m) {
    v.x += __shfl_xor(v.x, m, 64);
    v.y += __shfl_xor(v.y, m, 64);
    v.z += __shfl_xor(v.z, m, 64);
    v.w += __shfl_xor(v.w, m, 64);
    return v;
}
#define FMA4(A, S, B) \
    A.x = fmaf(S, B.x, A.x); A.y = fmaf(S, B.y, A.y); \
    A.z = fmaf(S, B.z, A.z); A.w = fmaf(S, B.w, A.w);

// ---- k1: {LN1 (blocks 0..31)} | {proj with LDS-staged double-buffered W chunks}
__global__ __launch_bounds__(512) void k1(
    const float* __restrict__ x, const float* __restrict__ g1,
    const float* __restrict__ b1, const float* __restrict__ emb,
    const float* __restrict__ Wq, const float* __restrict__ Wk,
    const float* __restrict__ Wv, const float* __restrict__ Wo,
    float* __restrict__ hbuf, float* __restrict__ EqT,
    float* __restrict__ Ekg, float* __restrict__ Evo)
{
    __shared__ float semb[4096];        // 16 KB: emb tile / LN reduce scratch
    __shared__ float swb[2][3][1088];   // 26.1 KB: 2 buf x {q,k,v} x (16 d x 68 pad)
    const int bid = blockIdx.x, tid = threadIdx.x;
    const int wid = tid >> 6, lane = tid & 63;
    if (bid < Bn) {
        float2 v = ((const float2*)(x + bid * Fn))[tid];
        float s = wsum(v.x + v.y);
        if (lane == 0) semb[wid] = s;
        __syncthreads();
        float mu = 0.f;
#pragma unroll
        for (int w = 0; w < 8; w++) mu += semb[w];
        mu *= (1.f / Fn);
        float dx = v.x - mu, dy = v.y - mu;
        float vs = wsum(dx * dx + dy * dy);
        __syncthreads();
        if (lane == 0) semb[wid] = vs;
        __syncthreads();
        float var = 0.f;
#pragma unroll
        for (int w = 0; w < 8; w++) var += semb[w];
        var *= (1.f / Fn);
        float rs = rsqrtf(var + LN_EPS);
        float2 gv = ((const float2*)g1)[tid];
        float2 bv = ((const float2*)b1)[tid];
        float2 o;
        o.x = dx * rs * gv.x + bv.x;
        o.y = dy * rs * gv.y + bv.y;
        ((float2*)(hbuf + bid * Fn))[tid] = o;
    } else {
        const int idx = bid - Bn;        // 0..255
        const int h = idx >> 6, f0 = (idx & 63) * 16;
        // stage emb tile (16 rows x 256)
        const float4* e4 = (const float4*)(emb + (size_t)f0 * Dn);
        float4* s4 = (float4*)semb;
        s4[tid] = e4[tid];
        s4[tid + 512] = e4[tid + 512];
        const int es = lane & 15, gs = lane >> 4;
        float4 wo4 = *(const float4*)&Wo[h * En + es * 4];
        const float* wqa = Wq + (size_t)h * Dn * En;
        const float* wka = Wk + (size_t)h * Dn * En;
        const float* wva = Wv + (size_t)h * Dn * En;
        // staging roles: threads 0..255 carry Wq; 256..511 carry Wk+Wv
        const int sd = (tid & 255) >> 4;     // d-row 0..15
        const int se = (tid & 15) * 4;       // e offset
        const bool lo = tid < 256;
        float4 rq, rk, rv;
        const int fl = wid * 2;
        float4 aq0 = {0,0,0,0}, aq1 = {0,0,0,0};
        float4 ak0 = {0,0,0,0}, ak1 = {0,0,0,0};
        float4 av0 = {0,0,0,0}, av1 = {0,0,0,0};
        // chunk 0
        {
            size_t off = ((size_t)sd) * En + se;
            if (lo) rq = *(const float4*)&wqa[off];
            else { rk = *(const float4*)&wka[off]; rv = *(const float4*)&wva[off]; }
            if (lo) *(float4*)&swb[0][0][sd * 68 + se] = rq;
            else {
                *(float4*)&swb[0][1][sd * 68 + se] = rk;
                *(float4*)&swb[0][2][sd * 68 + se] = rv;
            }
        }
        __syncthreads();
        for (int c = 0; c < 16; c++) {
            if (c < 15) {
                size_t off = ((size_t)((c + 1) * 16 + sd)) * En + se;
                if (lo) rq = *(const float4*)&wqa[off];
                else { rk = *(const float4*)&wka[off]; rv = *(const float4*)&wva[off]; }
            }
            const int pb = c & 1;
            const float* bq = swb[pb][0];
            const float* bk = swb[pb][1];
            const float* bv_ = swb[pb][2];
#pragma unroll
            for (int d0 = 0; d0 < 16; d0 += 4) {
                int d = d0 + gs;
                float4 q4 = *(const float4*)&bq[d * 68 + es * 4];
                float4 k4 = *(const float4*)&bk[d * 68 + es * 4];
                float4 v4 = *(const float4*)&bv_[d * 68 + es * 4];
                float e0 = semb[fl * 256 + c * 16 + d];
                float e1 = semb[(fl + 1) * 256 + c * 16 + d];
                FMA4(aq0, e0, q4); FMA4(aq1, e1, q4);
                FMA4(ak0, e0, k4); FMA4(ak1, e1, k4);
                FMA4(av0, e0, v4); FMA4(av1, e1, v4);
            }
            if (c < 15) {
                const int nb = (c + 1) & 1;
                if (lo) *(float4*)&swb[nb][0][sd * 68 + se] = rq;
                else {
                    *(float4*)&swb[nb][1][sd * 68 + se] = rk;
                    *(float4*)&swb[nb][2][sd * 68 + se] = rv;
                }
                __syncthreads();
            }
        }
        aq0 = xr4(aq0, 16); aq0 = xr4(aq0, 32);
        aq1 = xr4(aq1, 16); aq1 = xr4(aq1, 32);
        ak0 = xr4(ak0, 16); ak0 = xr4(ak0, 32);
        ak1 = xr4(ak1, 16); ak1 = xr4(ak1, 32);
        av0 = xr4(av0, 16); av0 = xr4(av0, 32);
        av1 = xr4(av1, 16); av1 = xr4(av1, 32);
        float p0 = av0.x * wo4.x + av0.y * wo4.y + av0.z * wo4.z + av0.w * wo4.w;
        float p1 = av1.x * wo4.x + av1.y * wo4.y + av1.z * wo4.z + av1.w * wo4.w;
#pragma unroll
        for (int m = 1; m < 16; m <<= 1) {
            p0 += __shfl_xor(p0, m, 64);
            p1 += __shfl_xor(p1, m, 64);
        }
        int f = f0 + fl;
        if (lane == 0) { Evo[h * Fn + f] = p0; Evo[h * Fn + f + 1] = p1; }
        if (gs == 0) {
            *(float4*)&Ekg[((size_t)h * Fn + f) * En + es * 4] = ak0;
            *(float4*)&Ekg[((size_t)h * Fn + f + 1) * En + es * 4] = ak1;
            const float sc = 0.125f;
            EqT[((size_t)h * En + es * 4 + 0) * Fn + f] = aq0.x * sc;
            EqT[((size_t)h * En + es * 4 + 1) * Fn + f] = aq0.y * sc;
            EqT[((size_t)h * En + es * 4 + 2) * Fn + f] = aq0.z * sc;
            EqT[((size_t)h * En + es * 4 + 3) * Fn + f] = aq0.w * sc;
            EqT[((size_t)h * En + es * 4 + 0) * Fn + f + 1] = aq1.x * sc;
            EqT[((size_t)h * En + es * 4 + 1) * Fn + f + 1] = aq1.y * sc;
            EqT[((size_t)h * En + es * 4 + 2) * Fn + f + 1] = aq1.z * sc;
            EqT[((size_t)h * En + es * 4 + 3) * Fn + f + 1] = aq1.w * sc;
        }
    }
}

// ---- k2: TT8[gc][h][c][e] (512 blocks) ----
__global__ __launch_bounds__(256) void k2(
    const float* __restrict__ hbuf, const float* __restrict__ Evo,
    const float* __restrict__ Ekg, float* __restrict__ TT8)
{
    const int bid = blockIdx.x, tid = threadIdx.x;
    const int wid = tid >> 6, lane = tid & 63;
    const int u = bid * 4 + wid;                  // 0..2047
    const int gc = u >> 8, hh = (u >> 6) & 3, c = u & 63;
    const int es = lane & 15, gs = lane >> 4;
    const float* ekb = Ekg + ((size_t)hh * Fn + gc * 128) * En + es * 4;
    float4 acc = {0, 0, 0, 0};
    if (c < Bn) {
        const float* rp = hbuf + (size_t)c * Fn + gc * 128;
#pragma unroll 8
        for (int g0 = 0; g0 < 128; g0 += 4) {
            int g = g0 + gs;
            float r = rp[g];
            float4 ek = *(const float4*)&ekb[(size_t)g * En];
            FMA4(acc, r, ek);
        }
    } else {
        const float* hp = hbuf + (size_t)(c - Bn) * Fn + gc * 128;
        const float* ep = Evo + hh * Fn + gc * 128;
#pragma unroll 8
        for (int g0 = 0; g0 < 128; g0 += 4) {
            int g = g0 + gs;
            float hv = hp[g];
            float r = hv * hv * ep[g];
            float4 ek = *(const float4*)&ekb[(size_t)g * En];
            FMA4(acc, r, ek);
        }
    }
    acc = xr4(acc, 16); acc = xr4(acc, 32);
    if (gs == 0)
        *(float4*)&TT8[(((size_t)gc * Hn + hh) * 64 + c) * 64 + es * 4] = acc;
}

// ---- k3: attn combine + residual + LN2; writes out-base (=xmid+bf2) and h2T
__global__ __launch_bounds__(1024) void k3(
    const float* __restrict__ x, const float* __restrict__ hbuf,
    const float* __restrict__ TT8, const float* __restrict__ EqT,
    const float* __restrict__ Evo, const float* __restrict__ bo,
    const float* __restrict__ g2, const float* __restrict__ b2,
    const float* __restrict__ bf2,
    float* __restrict__ out, float* __restrict__ h2T)
{
    __shared__ float tt[512];      // [cIsN][h][e]
    __shared__ float sp[Hn][16];
    __shared__ float red[16];
    __shared__ float s0l[Hn];
    const int b = blockIdx.x, tid = threadIdx.x;
    const int wid = tid >> 6, lane = tid & 63;
    if (tid < 512) {
        int cIsN = tid >> 8, hh = (tid >> 6) & 3, e = tid & 63;
        int c = cIsN ? (Bn + b) : b;
        float v = 0.f;
#pragma unroll
        for (int gc = 0; gc < 8; gc++)
            v += TT8[(((size_t)gc * Hn + hh) * 64 + c) * 64 + e];
        tt[tid] = v;
    }
    const int f = tid;
    float hf = hbuf[b * Fn + f];
    float pp[Hn];
#pragma unroll
    for (int hh = 0; hh < Hn; hh++) pp[hh] = hf * Evo[hh * Fn + f];
#pragma unroll
    for (int hh = 0; hh < Hn; hh++) {
        float t = wsum(pp[hh]);
        if (lane == 0) sp[hh][wid] = t;
    }
    __syncthreads();
    if (tid < Hn) {
        float s = 0.f;
#pragma unroll
        for (int w = 0; w < 16; w++) s += sp[tid][w];
        s0l[tid] = s;
    }
    __syncthreads();
    float xv = x[b * Fn + f] + bo[0];
#pragma unroll
    for (int hh = 0; hh < Hn; hh++) {
        float zd = 0.f, zn = 0.f;
        const float* eqb = EqT + (size_t)hh * En * Fn + f;
#pragma unroll 8
        for (int e = 0; e < En; e++) {
            float eq = eqb[(size_t)e * Fn];
            zd = fmaf(eq, tt[hh * 64 + e], zd);
            zn = fmaf(eq, tt[256 + hh * 64 + e], zn);
        }
        xv += (s0l[hh] + hf * zn) / (1024.0f + hf * zd);
    }
    float s = wsum(xv);
    if (lane == 0) red[wid] = s;
    __syncthreads();
    float mu = 0.f;
#pragma unroll
    for (int w = 0; w < 16; w++) mu += red[w];
    mu *= (1.f / Fn);
    float dx = xv - mu;
    float vs = wsum(dx * dx);
    __syncthreads();
    if (lane == 0) red[wid] = vs;
    __syncthreads();
    float var = 0.f;
#pragma unroll
    for (int w = 0; w < 16; w++) var += red[w];
    var *= (1.f / Fn);
    float rs = rsqrtf(var + LN_EPS);
    out[b * Fn + f] = xv + bf2[f];
    h2T[f * Bn + b] = dx * rs * g2[f] + b2[f];
}

// ---- k4: ffn1 partials. grid (16 jt, 16 fc), 512 thr.
__global__ __launch_bounds__(512) void k4(
    const float* __restrict__ h2T, const float* __restrict__ W1,
    float* __restrict__ C1p)
{
    __shared__ float h2s[64 * 32];   // 8 KB: [f][b]
    const int jt = blockIdx.x, fc = blockIdx.y;
    const int tid = threadIdx.x;
    const int wid = tid >> 6, lane = tid & 63;
    const int f0 = fc * 64;
    {
        int fr = tid >> 3, b4 = (tid & 7) * 4;
        *(float4*)&h2s[fr * 32 + b4] = *(const float4*)&h2T[(size_t)(f0 + fr) * Bn + b4];
    }
    __syncthreads();
    const int j4 = jt * 256 + lane * 4;
    const int bg = wid * 4;
    const float* wb = W1 + (size_t)f0 * FFn + j4;
    float4 a0 = {0,0,0,0}, a1 = {0,0,0,0}, a2 = {0,0,0,0}, a3 = {0,0,0,0};
#pragma unroll 8
    for (int f = 0; f < 64; f++) {
        float4 w4 = *(const float4*)&wb[(size_t)f * FFn];
        float4 hb = *(const float4*)&h2s[f * 32 + bg];
        FMA4(a0, hb.x, w4);
        FMA4(a1, hb.y, w4);
        FMA4(a2, hb.z, w4);
        FMA4(a3, hb.w, w4);
    }
    float* cp = C1p + ((size_t)fc * Bn + bg) * FFn + j4;
    *(float4*)&cp[0 * FFn] = a0;
    *(float4*)&cp[1 * FFn] = a1;
    *(float4*)&cp[2 * FFn] = a2;
    *(float4*)&cp[3 * FFn] = a3;
}

// ---- k4b: UT[j][b] = gelu(bf1[j] + sum_fc C1p[fc][b][j]).
__global__ __launch_bounds__(256) void k4b(
    const float* __restrict__ C1p, const float* __restrict__ bf1,
    float* __restrict__ UT)
{
    const int b = blockIdx.x >> 1, jh = blockIdx.x & 1;
    const int j8 = jh * 2048 + threadIdx.x * 8;
    float4 s0 = *(const float4*)&bf1[j8];
    float4 s1 = *(const float4*)&bf1[j8 + 4];
    const float* cb = C1p + (size_t)b * FFn + j8;
#pragma unroll
    for (int fc = 0; fc < 16; fc++) {
        float4 c0 = *(const float4*)&cb[(size_t)fc * Bn * FFn];
        float4 c1 = *(const float4*)&cb[(size_t)fc * Bn * FFn + 4];
        s0.x += c0.x; s0.y += c0.y; s0.z += c0.z; s0.w += c0.w;
        s1.x += c1.x; s1.y += c1.y; s1.z += c1.z; s1.w += c1.w;
    }
    const float kk = 0.70710678118654752f;
    float u[8] = {s0.x, s0.y, s0.z, s0.w, s1.x, s1.y, s1.z, s1.w};
#pragma unroll
    for (int r = 0; r < 8; r++)
        UT[(size_t)(j8 + r) * Bn + b] = 0.5f * u[r] * (1.f + erff(u[r] * kk));
}

// ---- k5: ffn2. grid 256 blocks (it 16 x jc 16), 512 thr.
__global__ __launch_bounds__(512) void k5(
    const float* __restrict__ UT, const float* __restrict__ W2,
    float* __restrict__ out)
{
    __shared__ float ug[256 * 32];   // 32 KB: [jj][b]
    const int it = blockIdx.x & 15, jc = blockIdx.x >> 4;
    const int tid = threadIdx.x;
    const int wid = tid >> 6, lane = tid & 63;
    {
        const float4* src = (const float4*)(UT + (size_t)jc * 256 * Bn);
        float4* dst = (float4*)ug;
#pragma unroll
        for (int k = 0; k < 4; k++)
            dst[k * 512 + tid] = src[k * 512 + tid];
    }
    __syncthreads();
    const int jg = lane >> 4, il = lane & 15;
    const int i0 = it * 64 + il * 4;
    const int bg = wid * 4;
    const float* wb = W2 + (size_t)(jc * 256 + jg) * Fn + i0;
    float4 a0 = {0,0,0,0}, a1 = {0,0,0,0}, a2 = {0,0,0,0}, a3 = {0,0,0,0};
#pragma unroll 8
    for (int jj0 = 0; jj0 < 256; jj0 += 4) {
        float4 w4 = *(const float4*)&wb[(size_t)jj0 * Fn];
        float4 u4 = *(const float4*)&ug[(jj0 + jg) * 32 + bg];
        FMA4(a0, u4.x, w4);
        FMA4(a1, u4.y, w4);
        FMA4(a2, u4.z, w4);
        FMA4(a3, u4.w, w4);
    }
    a0 = xr4(a0, 16); a0 = xr4(a0, 32);
    a1 = xr4(a1, 16); a1 = xr4(a1, 32);
    a2 = xr4(a2, 16); a2 = xr4(a2, 32);
    a3 = xr4(a3, 16); a3 = xr4(a3, 32);
    if (jg == 0) {
        float* ob = out + (size_t)bg * Fn + i0;
        atomicAdd(&ob[0 * Fn + 0], a0.x); atomicAdd(&ob[0 * Fn + 1], a0.y);
        atomicAdd(&ob[0 * Fn + 2], a0.z); atomicAdd(&ob[0 * Fn + 3], a0.w);
        atomicAdd(&ob[1 * Fn + 0], a1.x); atomicAdd(&ob[1 * Fn + 1], a1.y);
        atomicAdd(&ob[1 * Fn + 2], a1.z); atomicAdd(&ob[1 * Fn + 3], a1.w);
        atomicAdd(&ob[2 * Fn + 0], a2.x); atomicAdd(&ob[2 * Fn + 1], a2.y);
        atomicAdd(&ob[2 * Fn + 2], a2.z); atomicAdd(&ob[2 * Fn + 3], a2.w);
        atomicAdd(&ob[3 * Fn + 0], a3.x); atomicAdd(&ob[3 * Fn + 1], a3.y);
        atomicAdd(&ob[3 * Fn + 2], a3.z); atomicAdd(&ob[3 * Fn + 3], a3.w);
    }
}

extern "C" void kernel_launch(void* const* d_in, const int* in_sizes, int n_in,
                              void* d_out, int out_size, void* d_ws, size_t ws_size,
                              hipStream_t stream) {
    (void)in_sizes; (void)n_in; (void)out_size; (void)ws_size;
    const float* x   = (const float*)d_in[0];
    const float* emb = (const float*)d_in[1];
    const float* Wq  = (const float*)d_in[2];
    const float* Wk  = (const float*)d_in[3];
    const float* Wv  = (const float*)d_in[4];
    const float* Wo  = (const float*)d_in[5];
    const float* bo  = (const float*)d_in[6];
    const float* g1  = (const float*)d_in[7];
    const float* b1  = (const float*)d_in[8];
    const float* g2  = (const float*)d_in[9];
    const float* b2  = (const float*)d_in[10];
    const float* W1  = (const float*)d_in[11];
    const float* bf1 = (const float*)d_in[12];
    const float* W2  = (const float*)d_in[13];
    const float* bf2 = (const float*)d_in[14];
    float* out = (float*)d_out;

    float* ws = (float*)d_ws;
    size_t o = 0;
    float* EqT  = ws + o; o += (size_t)Hn * En * Fn;        // 262144
    float* Ekg  = ws + o; o += (size_t)Hn * Fn * En;        // 262144
    float* Evo  = ws + o; o += (size_t)Hn * Fn;             // 4096
    float* hbuf = ws + o; o += (size_t)Bn * Fn;             // 32768
    float* TT8  = ws + o; o += (size_t)8 * Hn * 64 * 64;    // 131072
    float* h2T  = ws + o; o += (size_t)Fn * Bn;             // 32768
    float* C1p  = ws + o; o += (size_t)16 * Bn * FFn;       // 2097152
    float* UT   = ws + o; o += (size_t)FFn * Bn;            // 131072

    k1<<<dim3(Bn + 256), 512, 0, stream>>>(x, g1, b1, emb, Wq, Wk, Wv, Wo,
                                           hbuf, EqT, Ekg, Evo);
    k2<<<dim3(512), 256, 0, stream>>>(hbuf, Evo, Ekg, TT8);
    k3<<<dim3(Bn), 1024, 0, stream>>>(x, hbuf, TT8, EqT, Evo, bo, g2, b2, bf2,
                                      out, h2T);
    k4<<<dim3(16, 16), 512, 0, stream>>>(h2T, W1, C1p);
    k4b<<<dim3(64), 256, 0, stream>>>(C1p, bf1, UT);
    k5<<<dim3(256), 512, 0, stream>>>(UT, W2, out);
}